// Round 1
// baseline (270.814 us; speedup 1.0000x reference)
//
#include <hip/hip_runtime.h>
#include <math.h>

#define NN 50000
#define NE 800000
#define FIN 256
#define FOUT 64
#define HEADS 4
#define HF 256   // HEADS*FOUT

typedef unsigned short u16;
typedef unsigned int u32;
typedef __attribute__((ext_vector_type(4))) u16 u16x4;
typedef __attribute__((ext_vector_type(8))) u16 u16x8;
typedef __attribute__((ext_vector_type(8))) short short8;
typedef __attribute__((ext_vector_type(4))) float f32x4;

__device__ __forceinline__ u16 f2bf(float x) {
  u32 u = __float_as_uint(x);
  u += 0x7fffu + ((u >> 16) & 1u);          // RNE
  return (u16)(u >> 16);
}
__device__ __forceinline__ float bf2f(u16 u) {
  return __uint_as_float(((u32)u) << 16);
}
__device__ __forceinline__ void gload_lds16(u16* lds, const u16* g) {
  __builtin_amdgcn_global_load_lds(
      (const __attribute__((address_space(1))) u32*)g,
      (__attribute__((address_space(3))) u32*)lds, 16, 0, 0);
}

// ---------------- K0a: cast x (fp32 -> bf16), 4 elems/thread ----------------
__global__ __launch_bounds__(256) void cast_x_k(const float* __restrict__ x,
                                                u16* __restrict__ xb) {
  int gid = blockIdx.x * 256 + threadIdx.x;   // grid sized exactly: 3,200,000
  float4 v = ((const float4*)x)[gid];
  u16x4 o = { f2bf(v.x), f2bf(v.y), f2bf(v.z), f2bf(v.w) };
  ((u16x4*)xb)[gid] = o;
}

// ---------------- K0b: build B^T bf16 [HF rows][FIN cols]: Bt[ho][f] = W[h][f][o]
__global__ __launch_bounds__(256) void make_bt_k(const float* __restrict__ W,
                                                 u16* __restrict__ Bt) {
  int t = blockIdx.x * 256 + threadIdx.x;     // exactly 65536
  int ho = t >> 8, f = t & 255;
  int h = ho >> 6, o = ho & 63;
  Bt[t] = f2bf(W[h * (FIN * FOUT) + f * FOUT + o]);
}

// ---------------- K1: bf16 MFMA GEMM: C[m][ho] = sum_f xb[m][f]*Bt[ho][f] ----
// 128x128 tile, BK=64, 4 waves (2x2), m97-style global_load_lds staging.
__global__ __launch_bounds__(256) void gemm_k(const u16* __restrict__ A,   // [M][256]
                                              const u16* __restrict__ Bt,  // [256][256]
                                              u16* __restrict__ C,         // [M][256] bf16
                                              int M) {
  __shared__ __align__(16) u16 smA[128 * 64];
  __shared__ __align__(16) u16 smB[128 * 64];
  const int tid = threadIdx.x;
  const int tm = blockIdx.x >> 1, tn = blockIdx.x & 1;
  const int m0 = tm * 128, n0 = tn * 128;
  const int lane = tid & 63, wid = tid >> 6;
  const int wr = wid >> 1, wc = wid & 1;
  const int arow = tid >> 3;            // 0..31 within a 4KB chunk
  const int acol = (tid & 7) * 8;       // element col (0..56 step 8)
  f32x4 acc[4][4] = {};

  for (int k0 = 0; k0 < FIN; k0 += 64) {
#pragma unroll
    for (int c = 0; c < 4; ++c) {
      int row = m0 + c * 32 + arow;
      if (row > M - 1) row = M - 1;     // clamp (stores are guarded)
      gload_lds16(&smA[(c * 32 + arow) * 64 + acol], A + row * 256 + k0 + acol);
    }
#pragma unroll
    for (int c = 0; c < 4; ++c) {
      int row = n0 + c * 32 + arow;     // < 256 always
      gload_lds16(&smB[(c * 32 + arow) * 64 + acol], Bt + row * 256 + k0 + acol);
    }
    asm volatile("s_waitcnt vmcnt(0)" ::: "memory");
    __syncthreads();
#pragma unroll
    for (int kk = 0; kk < 2; ++kk) {
      const int kb = kk * 32 + (lane >> 4) * 8;
      short8 aF[4], bF[4];
#pragma unroll
      for (int mi = 0; mi < 4; ++mi)
        aF[mi] = *(const short8*)&smA[(wr * 64 + mi * 16 + (lane & 15)) * 64 + kb];
#pragma unroll
      for (int ni = 0; ni < 4; ++ni)
        bF[ni] = *(const short8*)&smB[(wc * 64 + ni * 16 + (lane & 15)) * 64 + kb];
#pragma unroll
      for (int mi = 0; mi < 4; ++mi)
#pragma unroll
        for (int ni = 0; ni < 4; ++ni)
          acc[mi][ni] = __builtin_amdgcn_mfma_f32_16x16x32_bf16(aF[mi], bF[ni], acc[mi][ni], 0, 0, 0);
    }
    __syncthreads();
  }
  // epilogue: D col = lane&15, row = (lane>>4)*4 + r
#pragma unroll
  for (int mi = 0; mi < 4; ++mi) {
#pragma unroll
    for (int ni = 0; ni < 4; ++ni) {
      f32x4 a = acc[mi][ni];
#pragma unroll
      for (int r = 0; r < 4; ++r) {
        int row = m0 + wr * 64 + mi * 16 + (lane >> 4) * 4 + r;
        if (row < M) {
          int col = n0 + wc * 64 + ni * 16 + (lane & 15);
          C[row * 256 + col] = f2bf(a[r]);
        }
      }
    }
  }
}

// ---------------- K2: per-(node,head) logits s_self/s_neigh ------------------
__global__ __launch_bounds__(256) void slogit_k(const u16* __restrict__ fb,
                                                const float* __restrict__ a_self,
                                                const float* __restrict__ a_neigh,
                                                float* __restrict__ sself,
                                                float* __restrict__ sneigh) {
  int gid = blockIdx.x * 256 + threadIdx.x;
  if (gid >= NN * HEADS) return;
  int n = gid >> 2, h = gid & 3;
  const u16* f = fb + n * HF + h * FOUT;
  const float* as = a_self + h * FOUT;
  const float* an = a_neigh + h * FOUT;
  float ds = 0.f, dn = 0.f;
#pragma unroll
  for (int j = 0; j < FOUT; j += 8) {
    u16x8 v = *(const u16x8*)(f + j);
#pragma unroll
    for (int q = 0; q < 8; ++q) {
      float xv = bf2f(v[q]);
      ds = fmaf(xv, as[j + q], ds);
      dn = fmaf(xv, an[j + q], dn);
    }
  }
  sself[gid] = ds;
  sneigh[gid] = dn;
}

// ---------------- K3: CSR build ---------------------------------------------
__global__ __launch_bounds__(256) void zero_k(int* __restrict__ p, int n) {
  int i = blockIdx.x * 256 + threadIdx.x;
  if (i < n) p[i] = 0;
}
__global__ __launch_bounds__(256) void hist_k(const int* __restrict__ erow,
                                              int* __restrict__ counts) {
  int e = blockIdx.x * 256 + threadIdx.x;   // exactly NE
  atomicAdd(&counts[erow[e]], 1);
}
__global__ __launch_bounds__(256) void scan1_k(const int* __restrict__ counts,
                                               int* __restrict__ rowptr,
                                               int* __restrict__ part, int n) {
  __shared__ int buf[256];
  int t = threadIdx.x, i = blockIdx.x * 256 + t;
  int v = (i < n) ? counts[i] : 0;
  buf[t] = v;
  __syncthreads();
  for (int off = 1; off < 256; off <<= 1) {
    int tmp = (t >= off) ? buf[t - off] : 0;
    __syncthreads();
    buf[t] += tmp;
    __syncthreads();
  }
  if (i < n) rowptr[i] = buf[t] - v;        // block-local exclusive
  if (t == 255) part[blockIdx.x] = buf[255];
}
__global__ __launch_bounds__(256) void scan2_k(int* __restrict__ part,
                                               int* __restrict__ rowptr,
                                               int nb, int n) {
  __shared__ int buf[256];
  int t = threadIdx.x;
  int v = (t < nb) ? part[t] : 0;
  buf[t] = v;
  __syncthreads();
  for (int off = 1; off < 256; off <<= 1) {
    int tmp = (t >= off) ? buf[t - off] : 0;
    __syncthreads();
    buf[t] += tmp;
    __syncthreads();
  }
  if (t < nb) part[t] = buf[t] - v;         // exclusive block offsets
  if (t == 255) rowptr[n] = buf[255];       // grand total
}
__global__ __launch_bounds__(256) void scan3_k(int* __restrict__ rowptr,
                                               int* __restrict__ cursor,
                                               const int* __restrict__ part, int n) {
  int i = blockIdx.x * 256 + threadIdx.x;
  if (i < n) {
    int r = rowptr[i] + part[blockIdx.x];
    rowptr[i] = r;
    cursor[i] = r;
  }
}
__global__ __launch_bounds__(256) void scatter_k(const int* __restrict__ erow,
                                                 const int* __restrict__ ecol,
                                                 const float* __restrict__ adj,
                                                 int* __restrict__ cursor,
                                                 int* __restrict__ scol,
                                                 float* __restrict__ sadj) {
  int e = blockIdx.x * 256 + threadIdx.x;   // exactly NE
  int r = erow[e];
  int p = atomicAdd(&cursor[r], 1);
  scol[p] = ecol[e];
  sadj[p] = adj[e];
}

// ---------------- K4: per-node softmax + aggregate + bias + relu ------------
// one block per node; wave h owns head h (lane = output feature).
#define CH 128
__global__ __launch_bounds__(256) void node_k(const int* __restrict__ rowptr,
                                              const int* __restrict__ scol,
                                              const float* __restrict__ sadj,
                                              const float* __restrict__ sself,
                                              const float* __restrict__ sneigh,
                                              const u16* __restrict__ fb,
                                              const float* __restrict__ bias,
                                              float* __restrict__ out) {
  __shared__ int col_s[CH];
  __shared__ float adj_s[CH];
  __shared__ float w_s[HEADS][CH];
  const int i = blockIdx.x;
  const int tid = threadIdx.x, lane = tid & 63, h = tid >> 6;
  const int beg = rowptr[i], deg = rowptr[i + 1] - beg;
  const float ss = sself[i * 4 + h];
  float m_run = -INFINITY, s_run = 0.f, acc = 0.f;

  for (int base = 0; base < deg; base += CH) {
    const int cnt = min(CH, deg - base);
    __syncthreads();                         // protect LDS from previous chunk
    for (int j = tid; j < cnt; j += 256) {
      col_s[j] = scol[beg + base + j];
      adj_s[j] = sadj[beg + base + j];
    }
    __syncthreads();
    // wave h: compute edge logits for its head
    float ev0 = -INFINITY, ev1 = -INFINITY;
    float cmax = -INFINITY;
    if (lane < cnt) {
      int col = col_s[lane];
      float z = ss + sneigh[col * 4 + h];
      ev0 = (z > 0.f ? z : 0.2f * z) * adj_s[lane];
      cmax = ev0;
    }
    if (lane + 64 < cnt) {
      int col = col_s[lane + 64];
      float z = ss + sneigh[col * 4 + h];
      ev1 = (z > 0.f ? z : 0.2f * z) * adj_s[lane + 64];
      cmax = fmaxf(cmax, ev1);
    }
#pragma unroll
    for (int off = 32; off; off >>= 1) cmax = fmaxf(cmax, __shfl_xor(cmax, off, 64));
    const float m_new = fmaxf(m_run, cmax);  // cnt>=1 -> finite
    const float scale = __expf(m_run - m_new);
    float psum = 0.f;
    if (lane < cnt) {
      float wv = __expf(ev0 - m_new);
      w_s[h][lane] = wv;
      psum += wv;
    }
    if (lane + 64 < cnt) {
      float wv = __expf(ev1 - m_new);
      w_s[h][lane + 64] = wv;
      psum += wv;
    }
#pragma unroll
    for (int off = 32; off; off >>= 1) psum += __shfl_xor(psum, off, 64);
    s_run = s_run * scale + psum;
    m_run = m_new;
    acc *= scale;
    // aggregate (wave-local: w_s written & read by the same wave)
    const u16* fbh = fb + h * FOUT + lane;
    for (int e = 0; e < cnt; ++e) {
      float wv = w_s[h][e];
      int col = col_s[e];
      acc = fmaf(wv, bf2f(fbh[col * HF]), acc);
    }
  }
  float res = (s_run > 0.f) ? acc / s_run : 0.f;
  res += bias[h * FOUT + lane];
  out[i * HF + h * FOUT + lane] = fmaxf(res, 0.f);
}

// ---------------- launch -----------------------------------------------------
extern "C" void kernel_launch(void* const* d_in, const int* in_sizes, int n_in,
                              void* d_out, int out_size, void* d_ws, size_t ws_size,
                              hipStream_t stream) {
  const float* x       = (const float*)d_in[0];
  const float* W       = (const float*)d_in[1];
  const float* a_self  = (const float*)d_in[2];
  const float* a_neigh = (const float*)d_in[3];
  const float* bias    = (const float*)d_in[4];
  const float* adj     = (const float*)d_in[5];
  const int*   erow    = (const int*)d_in[6];
  const int*   ecol    = (const int*)d_in[7];
  float* out = (float*)d_out;

  char* w = (char*)d_ws;
  u16*   xb     = (u16*)w;   w += 25600000;   // [NN][256] bf16
  u16*   Bt     = (u16*)w;   w += 131072;     // [256][256] bf16
  u16*   fb     = (u16*)w;   w += 25600000;   // feats bf16 [NN][256]
  float* sself  = (float*)w; w += 800000;     // [NN*4]
  float* sneigh = (float*)w; w += 800000;     // [NN*4]
  int*   counts = (int*)w;   w += 200064;
  int*   rowptr = (int*)w;   w += 200192;     // [NN+1]
  int*   cursor = (int*)w;   w += 200064;
  int*   scol   = (int*)w;   w += 3200000;    // [NE]
  float* sadj   = (float*)w; w += 3200000;    // [NE]
  int*   part   = (int*)w;   w += 1024;       // [196]

  const int SCAN_B = (NN + 255) / 256;        // 196

  cast_x_k<<<dim3((NN * FIN) / 4 / 256), dim3(256), 0, stream>>>(x, xb);
  make_bt_k<<<dim3(256), dim3(256), 0, stream>>>(W, Bt);
  zero_k<<<dim3(SCAN_B), dim3(256), 0, stream>>>(counts, NN);
  gemm_k<<<dim3(((NN + 127) / 128) * 2), dim3(256), 0, stream>>>(xb, Bt, fb, NN);
  hist_k<<<dim3(NE / 256), dim3(256), 0, stream>>>(erow, counts);
  scan1_k<<<dim3(SCAN_B), dim3(256), 0, stream>>>(counts, rowptr, part, NN);
  scan2_k<<<dim3(1), dim3(256), 0, stream>>>(part, rowptr, SCAN_B, NN);
  scan3_k<<<dim3(SCAN_B), dim3(256), 0, stream>>>(rowptr, cursor, part, NN);
  scatter_k<<<dim3(NE / 256), dim3(256), 0, stream>>>(erow, ecol, adj, cursor, scol, sadj);
  slogit_k<<<dim3((NN * HEADS + 255) / 256), dim3(256), 0, stream>>>(fb, a_self, a_neigh, sself, sneigh);
  node_k<<<dim3(NN), dim3(256), 0, stream>>>(rowptr, scol, sadj, sself, sneigh, fb, bias, out);
}

// Round 2
// 224.683 us; speedup vs baseline: 1.2053x; 1.2053x over previous
//
#include <hip/hip_runtime.h>
#include <math.h>

#define NN 50000
#define NE 800000
#define FIN 256
#define FOUT 64
#define HEADS 4
#define HF 256   // HEADS*FOUT

typedef unsigned short u16;
typedef unsigned int u32;
typedef __attribute__((ext_vector_type(4))) u16 u16x4;
typedef __attribute__((ext_vector_type(8))) u16 u16x8;
typedef __attribute__((ext_vector_type(8))) short short8;
typedef __attribute__((ext_vector_type(4))) float f32x4;

__device__ __forceinline__ u16 f2bf(float x) {
  u32 u = __float_as_uint(x);
  u += 0x7fffu + ((u >> 16) & 1u);          // RNE
  return (u16)(u >> 16);
}
__device__ __forceinline__ float bf2f(u16 u) {
  return __uint_as_float(((u32)u) << 16);
}
__device__ __forceinline__ void gload_lds16(u16* lds, const u16* g) {
  __builtin_amdgcn_global_load_lds(
      (const __attribute__((address_space(1))) u32*)g,
      (__attribute__((address_space(3))) u32*)lds, 16, 0, 0);
}
__device__ __forceinline__ float sel4(float4 v, int h) {
  float r = v.x;
  r = (h == 1) ? v.y : r;
  r = (h == 2) ? v.z : r;
  r = (h == 3) ? v.w : r;
  return r;
}

// ---------------- K0a: cast x (fp32 -> bf16), 4 elems/thread ----------------
__global__ __launch_bounds__(256) void cast_x_k(const float* __restrict__ x,
                                                u16* __restrict__ xb) {
  int gid = blockIdx.x * 256 + threadIdx.x;   // grid sized exactly
  float4 v = ((const float4*)x)[gid];
  u16x4 o = { f2bf(v.x), f2bf(v.y), f2bf(v.z), f2bf(v.w) };
  ((u16x4*)xb)[gid] = o;
}

// ---------------- K0b: build B^T bf16 [HF rows][FIN cols] -------------------
__global__ __launch_bounds__(256) void make_bt_k(const float* __restrict__ W,
                                                 u16* __restrict__ Bt) {
  int t = blockIdx.x * 256 + threadIdx.x;     // exactly 65536
  int ho = t >> 8, f = t & 255;
  int h = ho >> 6, o = ho & 63;
  Bt[t] = f2bf(W[h * (FIN * FOUT) + f * FOUT + o]);
}

// ---------------- K1: bf16 MFMA GEMM: C[m][ho] = sum_f xb[m][f]*Bt[ho][f] ----
__global__ __launch_bounds__(256) void gemm_k(const u16* __restrict__ A,
                                              const u16* __restrict__ Bt,
                                              u16* __restrict__ C,
                                              int M) {
  __shared__ __align__(16) u16 smA[128 * 64];
  __shared__ __align__(16) u16 smB[128 * 64];
  const int tid = threadIdx.x;
  const int tm = blockIdx.x >> 1, tn = blockIdx.x & 1;
  const int m0 = tm * 128, n0 = tn * 128;
  const int lane = tid & 63, wid = tid >> 6;
  const int wr = wid >> 1, wc = wid & 1;
  const int arow = tid >> 3;
  const int acol = (tid & 7) * 8;
  f32x4 acc[4][4] = {};

  for (int k0 = 0; k0 < FIN; k0 += 64) {
#pragma unroll
    for (int c = 0; c < 4; ++c) {
      int row = m0 + c * 32 + arow;
      if (row > M - 1) row = M - 1;
      gload_lds16(&smA[(c * 32 + arow) * 64 + acol], A + row * 256 + k0 + acol);
    }
#pragma unroll
    for (int c = 0; c < 4; ++c) {
      int row = n0 + c * 32 + arow;
      gload_lds16(&smB[(c * 32 + arow) * 64 + acol], Bt + row * 256 + k0 + acol);
    }
    asm volatile("s_waitcnt vmcnt(0)" ::: "memory");
    __syncthreads();
#pragma unroll
    for (int kk = 0; kk < 2; ++kk) {
      const int kb = kk * 32 + (lane >> 4) * 8;
      short8 aF[4], bF[4];
#pragma unroll
      for (int mi = 0; mi < 4; ++mi)
        aF[mi] = *(const short8*)&smA[(wr * 64 + mi * 16 + (lane & 15)) * 64 + kb];
#pragma unroll
      for (int ni = 0; ni < 4; ++ni)
        bF[ni] = *(const short8*)&smB[(wc * 64 + ni * 16 + (lane & 15)) * 64 + kb];
#pragma unroll
      for (int mi = 0; mi < 4; ++mi)
#pragma unroll
        for (int ni = 0; ni < 4; ++ni)
          acc[mi][ni] = __builtin_amdgcn_mfma_f32_16x16x32_bf16(aF[mi], bF[ni], acc[mi][ni], 0, 0, 0);
    }
    __syncthreads();
  }
#pragma unroll
  for (int mi = 0; mi < 4; ++mi) {
#pragma unroll
    for (int ni = 0; ni < 4; ++ni) {
      f32x4 a = acc[mi][ni];
#pragma unroll
      for (int r = 0; r < 4; ++r) {
        int row = m0 + wr * 64 + mi * 16 + (lane >> 4) * 4 + r;
        if (row < M) {
          int col = n0 + wc * 64 + ni * 16 + (lane & 15);
          C[row * 256 + col] = f2bf(a[r]);
        }
      }
    }
  }
}

// ---------------- K2: per-(node,head) logits --------------------------------
__global__ __launch_bounds__(256) void slogit_k(const u16* __restrict__ fb,
                                                const float* __restrict__ a_self,
                                                const float* __restrict__ a_neigh,
                                                float* __restrict__ sself,
                                                float* __restrict__ sneigh) {
  int gid = blockIdx.x * 256 + threadIdx.x;
  if (gid >= NN * HEADS) return;
  int n = gid >> 2, h = gid & 3;
  const u16* f = fb + n * HF + h * FOUT;
  const float* as = a_self + h * FOUT;
  const float* an = a_neigh + h * FOUT;
  float ds = 0.f, dn = 0.f;
#pragma unroll
  for (int j = 0; j < FOUT; j += 8) {
    u16x8 v = *(const u16x8*)(f + j);
#pragma unroll
    for (int q = 0; q < 8; ++q) {
      float xv = bf2f(v[q]);
      ds = fmaf(xv, as[j + q], ds);
      dn = fmaf(xv, an[j + q], dn);
    }
  }
  sself[gid] = ds;
  sneigh[gid] = dn;
}

// ---------------- K3: CSR build ---------------------------------------------
__global__ __launch_bounds__(256) void zero_k(int* __restrict__ p, int n) {
  int i = blockIdx.x * 256 + threadIdx.x;
  if (i < n) p[i] = 0;
}
__global__ __launch_bounds__(256) void hist_k(const int* __restrict__ erow,
                                              int* __restrict__ counts) {
  int e = blockIdx.x * 256 + threadIdx.x;
  atomicAdd(&counts[erow[e]], 1);
}
__global__ __launch_bounds__(256) void scan1_k(const int* __restrict__ counts,
                                               int* __restrict__ rowptr,
                                               int* __restrict__ part, int n) {
  __shared__ int buf[256];
  int t = threadIdx.x, i = blockIdx.x * 256 + t;
  int v = (i < n) ? counts[i] : 0;
  buf[t] = v;
  __syncthreads();
  for (int off = 1; off < 256; off <<= 1) {
    int tmp = (t >= off) ? buf[t - off] : 0;
    __syncthreads();
    buf[t] += tmp;
    __syncthreads();
  }
  if (i < n) rowptr[i] = buf[t] - v;
  if (t == 255) part[blockIdx.x] = buf[255];
}
__global__ __launch_bounds__(256) void scan2_k(int* __restrict__ part,
                                               int* __restrict__ rowptr,
                                               int nb, int n) {
  __shared__ int buf[256];
  int t = threadIdx.x;
  int v = (t < nb) ? part[t] : 0;
  buf[t] = v;
  __syncthreads();
  for (int off = 1; off < 256; off <<= 1) {
    int tmp = (t >= off) ? buf[t - off] : 0;
    __syncthreads();
    buf[t] += tmp;
    __syncthreads();
  }
  if (t < nb) part[t] = buf[t] - v;
  if (t == 255) rowptr[n] = buf[255];
}
__global__ __launch_bounds__(256) void scan3_k(int* __restrict__ rowptr,
                                               int* __restrict__ cursor,
                                               const int* __restrict__ part, int n) {
  int i = blockIdx.x * 256 + threadIdx.x;
  if (i < n) {
    int r = rowptr[i] + part[blockIdx.x];
    rowptr[i] = r;
    cursor[i] = r;
  }
}
__global__ __launch_bounds__(256) void scatter_k(const int* __restrict__ erow,
                                                 const int* __restrict__ ecol,
                                                 const float* __restrict__ adj,
                                                 int* __restrict__ cursor,
                                                 int2* __restrict__ edata) {
  int e = blockIdx.x * 256 + threadIdx.x;
  int r = erow[e];
  int p = atomicAdd(&cursor[r], 1);
  int2 v;
  v.x = ecol[e];
  v.y = __float_as_int(adj[e]);
  edata[p] = v;
}

// ---------------- K4: per-node softmax + aggregate + bias + relu ------------
// one WAVE per node (all 4 heads); lane l owns features [4l, 4l+4).
__global__ __launch_bounds__(256) void node2_k(const int* __restrict__ rowptr,
                                               const int2* __restrict__ edata,
                                               const float4* __restrict__ sneigh4,
                                               const float4* __restrict__ sself4,
                                               const u16* __restrict__ fb,
                                               const float* __restrict__ bias,
                                               float* __restrict__ out) {
  __shared__ float w_s[4][4][65];   // [wave][head][edge-slot], 65 breaks bank alias
  __shared__ int   c_s[4][64];
  const int tid = threadIdx.x, lane = tid & 63, w = tid >> 6;
  const int i = blockIdx.x * 4 + w;                 // grid = 12500, exact
  const int hl = lane >> 4;                          // this lane's head
  const int beg = rowptr[i], deg = rowptr[i + 1] - beg;
  const float4 ssv = sself4[i];                      // all-lane uniform

  float4 mvec = { -INFINITY, -INFINITY, -INFINITY, -INFINITY };
  float4 svec = { 0.f, 0.f, 0.f, 0.f };
  float4 acc  = { 0.f, 0.f, 0.f, 0.f };

  for (int base = 0; base < deg; base += 64) {
    const int cnt = min(64, deg - base);
    const int idx = beg + base + min(lane, cnt - 1); // clamped coalesced load
    int2 ed = edata[idx];
    const int   col = ed.x;
    const float adj = __int_as_float(ed.y);
    float4 nb = sneigh4[col];                        // 16B gather
    float4 ev;
    {
      float z0 = ssv.x + nb.x, z1 = ssv.y + nb.y, z2 = ssv.z + nb.z, z3 = ssv.w + nb.w;
      ev.x = (z0 > 0.f ? z0 : 0.2f * z0) * adj;
      ev.y = (z1 > 0.f ? z1 : 0.2f * z1) * adj;
      ev.z = (z2 > 0.f ? z2 : 0.2f * z2) * adj;
      ev.w = (z3 > 0.f ? z3 : 0.2f * z3) * adj;
      if (lane >= cnt) { ev.x = -INFINITY; ev.y = -INFINITY; ev.z = -INFINITY; ev.w = -INFINITY; }
    }
    // componentwise max-reduce over 64 lanes
    float4 cm = ev;
#pragma unroll
    for (int off = 32; off; off >>= 1) {
      cm.x = fmaxf(cm.x, __shfl_xor(cm.x, off, 64));
      cm.y = fmaxf(cm.y, __shfl_xor(cm.y, off, 64));
      cm.z = fmaxf(cm.z, __shfl_xor(cm.z, off, 64));
      cm.w = fmaxf(cm.w, __shfl_xor(cm.w, off, 64));
    }
    float4 mnew;
    mnew.x = fmaxf(mvec.x, cm.x); mnew.y = fmaxf(mvec.y, cm.y);
    mnew.z = fmaxf(mvec.z, cm.z); mnew.w = fmaxf(mvec.w, cm.w);
    float4 sc;
    sc.x = __expf(mvec.x - mnew.x); sc.y = __expf(mvec.y - mnew.y);
    sc.z = __expf(mvec.z - mnew.z); sc.w = __expf(mvec.w - mnew.w);
    float4 wv;
    wv.x = __expf(ev.x - mnew.x); wv.y = __expf(ev.y - mnew.y);
    wv.z = __expf(ev.z - mnew.z); wv.w = __expf(ev.w - mnew.w);
    float4 ps = wv;
#pragma unroll
    for (int off = 32; off; off >>= 1) {
      ps.x += __shfl_xor(ps.x, off, 64);
      ps.y += __shfl_xor(ps.y, off, 64);
      ps.z += __shfl_xor(ps.z, off, 64);
      ps.w += __shfl_xor(ps.w, off, 64);
    }
    svec.x = svec.x * sc.x + ps.x; svec.y = svec.y * sc.y + ps.y;
    svec.z = svec.z * sc.z + ps.z; svec.w = svec.w * sc.w + ps.w;
    mvec = mnew;
    // publish weights + cols to wave-local LDS (lanes>=cnt hold wv==0)
    c_s[w][lane] = col;
    w_s[w][0][lane] = wv.x; w_s[w][1][lane] = wv.y;
    w_s[w][2][lane] = wv.z; w_s[w][3][lane] = wv.w;
    const float scl = sel4(sc, hl);
    acc.x *= scl; acc.y *= scl; acc.z *= scl; acc.w *= scl;
    // aggregate: 4 gathers in flight per step
    const int cnt4 = (cnt + 3) & ~3;
    for (int e = 0; e < cnt4; e += 4) {
      int cq[4]; float wq[4];
#pragma unroll
      for (int q = 0; q < 4; ++q) {
        cq[q] = c_s[w][e + q];
        wq[q] = w_s[w][hl][e + q];
      }
      u16x4 f[4];
#pragma unroll
      for (int q = 0; q < 4; ++q)
        f[q] = *(const u16x4*)(fb + (size_t)cq[q] * HF + lane * 4);
#pragma unroll
      for (int q = 0; q < 4; ++q) {
        acc.x = fmaf(wq[q], bf2f(f[q][0]), acc.x);
        acc.y = fmaf(wq[q], bf2f(f[q][1]), acc.y);
        acc.z = fmaf(wq[q], bf2f(f[q][2]), acc.z);
        acc.w = fmaf(wq[q], bf2f(f[q][3]), acc.w);
      }
    }
  }
  const float s_l = sel4(svec, hl);
  const float r = (s_l > 0.f) ? __frcp_rn(s_l) : 0.f;
  float4 b4 = *(const float4*)(bias + lane * 4);     // bias flat [H][64] matches
  float4 o;
  o.x = fmaxf(fmaf(acc.x, r, b4.x), 0.f);
  o.y = fmaxf(fmaf(acc.y, r, b4.y), 0.f);
  o.z = fmaxf(fmaf(acc.z, r, b4.z), 0.f);
  o.w = fmaxf(fmaf(acc.w, r, b4.w), 0.f);
  ((float4*)out)[(size_t)i * 64 + lane] = o;
}

// ---------------- launch -----------------------------------------------------
extern "C" void kernel_launch(void* const* d_in, const int* in_sizes, int n_in,
                              void* d_out, int out_size, void* d_ws, size_t ws_size,
                              hipStream_t stream) {
  const float* x       = (const float*)d_in[0];
  const float* W       = (const float*)d_in[1];
  const float* a_self  = (const float*)d_in[2];
  const float* a_neigh = (const float*)d_in[3];
  const float* bias    = (const float*)d_in[4];
  const float* adj     = (const float*)d_in[5];
  const int*   erow    = (const int*)d_in[6];
  const int*   ecol    = (const int*)d_in[7];
  float* out = (float*)d_out;

  char* w = (char*)d_ws;
  u16*   xb     = (u16*)w;   w += 25600000;   // [NN][256] bf16
  u16*   Bt     = (u16*)w;   w += 131072;     // [256][256] bf16
  u16*   fb     = (u16*)w;   w += 25600000;   // feats bf16 [NN][256]
  float* sself  = (float*)w; w += 800000;     // [NN*4]
  float* sneigh = (float*)w; w += 800000;     // [NN*4]
  int*   counts = (int*)w;   w += 200064;
  int*   rowptr = (int*)w;   w += 200192;     // [NN+1]
  int*   cursor = (int*)w;   w += 200064;
  int2*  edata  = (int2*)w;  w += 6400000;    // [NE] {col, adj}
  int*   part   = (int*)w;   w += 1024;

  const int SCAN_B = (NN + 255) / 256;        // 196

  cast_x_k<<<dim3((NN * FIN) / 4 / 256), dim3(256), 0, stream>>>(x, xb);
  make_bt_k<<<dim3(256), dim3(256), 0, stream>>>(W, Bt);
  zero_k<<<dim3(SCAN_B), dim3(256), 0, stream>>>(counts, NN);
  gemm_k<<<dim3(((NN + 127) / 128) * 2), dim3(256), 0, stream>>>(xb, Bt, fb, NN);
  hist_k<<<dim3(NE / 256), dim3(256), 0, stream>>>(erow, counts);
  scan1_k<<<dim3(SCAN_B), dim3(256), 0, stream>>>(counts, rowptr, part, NN);
  scan2_k<<<dim3(1), dim3(256), 0, stream>>>(part, rowptr, SCAN_B, NN);
  scan3_k<<<dim3(SCAN_B), dim3(256), 0, stream>>>(rowptr, cursor, part, NN);
  scatter_k<<<dim3(NE / 256), dim3(256), 0, stream>>>(erow, ecol, adj, cursor, edata);
  slogit_k<<<dim3((NN * HEADS + 255) / 256), dim3(256), 0, stream>>>(fb, a_self, a_neigh, sself, sneigh);
  node2_k<<<dim3(NN / 4), dim3(256), 0, stream>>>(rowptr, edata, (const float4*)sneigh,
                                                  (const float4*)sself, fb, bias, out);
}

// Round 3
// 196.173 us; speedup vs baseline: 1.3805x; 1.1453x over previous
//
#include <hip/hip_runtime.h>
#include <math.h>

#define NN 50000
#define NE 800000
#define FIN 256
#define FOUT 64
#define HEADS 4
#define HF 256   // HEADS*FOUT

typedef unsigned short u16;
typedef unsigned int u32;
typedef __attribute__((ext_vector_type(4))) u16 u16x4;
typedef __attribute__((ext_vector_type(8))) u16 u16x8;
typedef __attribute__((ext_vector_type(8))) short short8;
typedef __attribute__((ext_vector_type(4))) float f32x4;

__device__ __forceinline__ u16 f2bf(float x) {
  u32 u = __float_as_uint(x);
  u += 0x7fffu + ((u >> 16) & 1u);          // RNE
  return (u16)(u >> 16);
}
__device__ __forceinline__ float bf2f(u16 u) {
  return __uint_as_float(((u32)u) << 16);
}
__device__ __forceinline__ void gload_lds16(u16* lds, const u16* g) {
  __builtin_amdgcn_global_load_lds(
      (const __attribute__((address_space(1))) u32*)g,
      (__attribute__((address_space(3))) u32*)lds, 16, 0, 0);
}

// ---------------- K0: fused cast_x + make_bt + zero(counts) -----------------
#define CAST_B 12500
#define BT_B   256
#define ZERO_B 196
__global__ __launch_bounds__(256) void pre_k(const float* __restrict__ x,
                                             u16* __restrict__ xb,
                                             const float* __restrict__ W,
                                             u16* __restrict__ Bt,
                                             int* __restrict__ counts) {
  const int b = blockIdx.x, tid = threadIdx.x;
  if (b < CAST_B) {
    int gid = b * 256 + tid;                 // 3,200,000 float4 slots exactly
    float4 v = ((const float4*)x)[gid];
    u16x4 o = { f2bf(v.x), f2bf(v.y), f2bf(v.z), f2bf(v.w) };
    ((u16x4*)xb)[gid] = o;
  } else if (b < CAST_B + BT_B) {
    int t = (b - CAST_B) * 256 + tid;        // 65536 exactly
    int ho = t >> 8, f = t & 255;
    int h = ho >> 6, o = ho & 63;
    Bt[t] = f2bf(W[h * (FIN * FOUT) + f * FOUT + o]);
  } else {
    int i = (b - CAST_B - BT_B) * 256 + tid;
    if (i < NN) counts[i] = 0;
  }
}

// ---------------- K1: 128x256-tile bf16 MFMA GEMM + fused logits ------------
// 512 threads = 8 waves (2 row x 4 col); wave col-range = one head.
__global__ __launch_bounds__(512) void gemm_lg_k(const u16* __restrict__ A,   // [M][256]
                                                 const u16* __restrict__ Bt,  // [256][256]
                                                 u16* __restrict__ C,         // [M][256]
                                                 const float* __restrict__ a_self,
                                                 const float* __restrict__ a_neigh,
                                                 float* __restrict__ sself,
                                                 float* __restrict__ sneigh,
                                                 int M) {
  __shared__ __align__(16) u16 smA[128 * 64];   // 16 KB
  __shared__ __align__(16) u16 smB[256 * 64];   // 32 KB
  const int tid = threadIdx.x;
  const int m0 = blockIdx.x * 128;
  const int lane = tid & 63, wid = tid >> 6;
  const int wr = wid >> 2, wc = wid & 3;        // wave rows 64, cols 64 (head wc)
  const int arow = tid >> 3;                    // 0..63
  const int acol = (tid & 7) * 8;               // 0..56 step 8
  f32x4 acc[4][4] = {};

  for (int k0 = 0; k0 < FIN; k0 += 64) {
#pragma unroll
    for (int c = 0; c < 2; ++c) {               // A: 128 rows
      int row = m0 + c * 64 + arow;
      if (row > M - 1) row = M - 1;
      gload_lds16(&smA[(c * 64 + arow) * 64 + acol], A + (size_t)row * 256 + k0 + acol);
    }
#pragma unroll
    for (int c = 0; c < 4; ++c) {               // B: 256 rows
      int row = c * 64 + arow;
      gload_lds16(&smB[(c * 64 + arow) * 64 + acol], Bt + row * 256 + k0 + acol);
    }
    asm volatile("s_waitcnt vmcnt(0)" ::: "memory");
    __syncthreads();
#pragma unroll
    for (int kk = 0; kk < 2; ++kk) {
      const int kb = kk * 32 + (lane >> 4) * 8;
      short8 aF[4], bF[4];
#pragma unroll
      for (int mi = 0; mi < 4; ++mi)
        aF[mi] = *(const short8*)&smA[(wr * 64 + mi * 16 + (lane & 15)) * 64 + kb];
#pragma unroll
      for (int ni = 0; ni < 4; ++ni)
        bF[ni] = *(const short8*)&smB[(wc * 64 + ni * 16 + (lane & 15)) * 64 + kb];
#pragma unroll
      for (int mi = 0; mi < 4; ++mi)
#pragma unroll
        for (int ni = 0; ni < 4; ++ni)
          acc[mi][ni] = __builtin_amdgcn_mfma_f32_16x16x32_bf16(aF[mi], bF[ni], acc[mi][ni], 0, 0, 0);
    }
    __syncthreads();
  }
  // ---- store C (bf16) ----
#pragma unroll
  for (int mi = 0; mi < 4; ++mi) {
#pragma unroll
    for (int ni = 0; ni < 4; ++ni) {
      f32x4 a = acc[mi][ni];
      int col = wc * 64 + ni * 16 + (lane & 15);
#pragma unroll
      for (int r = 0; r < 4; ++r) {
        int row = m0 + wr * 64 + mi * 16 + (lane >> 4) * 4 + r;
        if (row < M) C[(size_t)row * 256 + col] = f2bf(a[r]);
      }
    }
  }
  // ---- fused logits: head h = wc; this wave's 64 cols are exactly head wc ----
  float asv[4], anv[4];
#pragma unroll
  for (int ni = 0; ni < 4; ++ni) {
    int col = wc * 64 + ni * 16 + (lane & 15);  // a_* flat [H][64] -> index col
    asv[ni] = a_self[col];
    anv[ni] = a_neigh[col];
  }
#pragma unroll
  for (int mi = 0; mi < 4; ++mi) {
#pragma unroll
    for (int r = 0; r < 4; ++r) {
      float ds = 0.f, dn = 0.f;
#pragma unroll
      for (int ni = 0; ni < 4; ++ni) {
        float v = acc[mi][ni][r];
        ds = fmaf(v, asv[ni], ds);
        dn = fmaf(v, anv[ni], dn);
      }
#pragma unroll
      for (int off = 1; off < 16; off <<= 1) {  // reduce over the 16 frag-cols
        ds += __shfl_xor(ds, off, 64);
        dn += __shfl_xor(dn, off, 64);
      }
      if ((lane & 15) == 0) {
        int row = m0 + wr * 64 + mi * 16 + (lane >> 4) * 4 + r;
        if (row < M) {
          sself[row * 4 + wc] = ds;
          sneigh[row * 4 + wc] = dn;
        }
      }
    }
  }
}

// ---------------- K2: CSR build ---------------------------------------------
__global__ __launch_bounds__(256) void hist_k(const int* __restrict__ erow,
                                              int* __restrict__ counts) {
  int e = blockIdx.x * 256 + threadIdx.x;
  atomicAdd(&counts[erow[e]], 1);
}
__global__ __launch_bounds__(256) void scan1_k(const int* __restrict__ counts,
                                               int* __restrict__ rowptr,
                                               int* __restrict__ part, int n) {
  __shared__ int buf[256];
  int t = threadIdx.x, i = blockIdx.x * 256 + t;
  int v = (i < n) ? counts[i] : 0;
  buf[t] = v;
  __syncthreads();
  for (int off = 1; off < 256; off <<= 1) {
    int tmp = (t >= off) ? buf[t - off] : 0;
    __syncthreads();
    buf[t] += tmp;
    __syncthreads();
  }
  if (i < n) rowptr[i] = buf[t] - v;
  if (t == 255) part[blockIdx.x] = buf[255];
}
__global__ __launch_bounds__(256) void scan2_k(int* __restrict__ part,
                                               int* __restrict__ rowptr,
                                               int nb, int n) {
  __shared__ int buf[256];
  int t = threadIdx.x;
  int v = (t < nb) ? part[t] : 0;
  buf[t] = v;
  __syncthreads();
  for (int off = 1; off < 256; off <<= 1) {
    int tmp = (t >= off) ? buf[t - off] : 0;
    __syncthreads();
    buf[t] += tmp;
    __syncthreads();
  }
  if (t < nb) part[t] = buf[t] - v;
  if (t == 255) rowptr[n] = buf[255];
}
__global__ __launch_bounds__(256) void scan3_k(int* __restrict__ rowptr,
                                               int* __restrict__ cursor,
                                               const int* __restrict__ part, int n) {
  int i = blockIdx.x * 256 + threadIdx.x;
  if (i < n) {
    int r = rowptr[i] + part[blockIdx.x];
    rowptr[i] = r;
    cursor[i] = r;
  }
}
__global__ __launch_bounds__(256) void scatter_k(const int* __restrict__ erow,
                                                 const int* __restrict__ ecol,
                                                 const float* __restrict__ adj,
                                                 int* __restrict__ cursor,
                                                 int2* __restrict__ edata) {
  int e = blockIdx.x * 256 + threadIdx.x;
  int r = erow[e];
  int p = atomicAdd(&cursor[r], 1);
  int2 v;
  v.x = ecol[e];
  v.y = __float_as_int(adj[e]);
  edata[p] = v;
}

// ---------------- K3: per-node softmax(no-max) + aggregate + bias + relu ----
// one WAVE per node; lane l owns features [4l,4l+4). Denominator recovered
// inside the aggregate loop (each lane sums its own head's weights).
__global__ __launch_bounds__(256) void node3_k(const int* __restrict__ rowptr,
                                               const int2* __restrict__ edata,
                                               const float4* __restrict__ sneigh4,
                                               const float4* __restrict__ sself4,
                                               const u16* __restrict__ fb,
                                               const float* __restrict__ bias,
                                               float* __restrict__ out) {
  __shared__ float4 w4_s[4][64];   // [wave][slot] -> 4 head weights
  __shared__ int    c_s[4][64];
  const int tid = threadIdx.x, lane = tid & 63, w = tid >> 6;
  const int i = blockIdx.x * 4 + w;                 // grid 12500, exact
  const int hl = lane >> 4;                          // this lane's head
  const int beg = rowptr[i], deg = rowptr[i + 1] - beg;
  const float4 ssv = sself4[i];
  const float* w_f = (const float*)&w4_s[w][0];
  float s_own = 0.f;
  float4 acc = { 0.f, 0.f, 0.f, 0.f };

  for (int base = 0; base < deg; base += 64) {
    const int cnt = min(64, deg - base);
    int2 ed = edata[beg + base + min(lane, cnt - 1)];
    const int col = ed.x;
    const float adj = __int_as_float(ed.y);
    float4 nb = sneigh4[col];                        // 16B gather
    float4 wv;
    {
      float z0 = ssv.x + nb.x, z1 = ssv.y + nb.y, z2 = ssv.z + nb.z, z3 = ssv.w + nb.w;
      float e0 = (z0 > 0.f ? z0 : 0.2f * z0) * adj;
      float e1 = (z1 > 0.f ? z1 : 0.2f * z1) * adj;
      float e2 = (z2 > 0.f ? z2 : 0.2f * z2) * adj;
      float e3 = (z3 > 0.f ? z3 : 0.2f * z3) * adj;
      wv.x = __expf(e0); wv.y = __expf(e1); wv.z = __expf(e2); wv.w = __expf(e3);
      if (lane >= cnt) { wv.x = 0.f; wv.y = 0.f; wv.z = 0.f; wv.w = 0.f; }
    }
    c_s[w][lane] = col;
    w4_s[w][lane] = wv;
    asm volatile("s_waitcnt lgkmcnt(0)" ::: "memory");
    const int cnt8 = (cnt + 7) & ~7;
    for (int e = 0; e < cnt8; e += 8) {
      int cq[8]; float wq[8];
#pragma unroll
      for (int q = 0; q < 8; ++q) {
        cq[q] = c_s[w][e + q];
        wq[q] = w_f[(e + q) * 4 + hl];
      }
      u16x4 f[8];
#pragma unroll
      for (int q = 0; q < 8; ++q)
        f[q] = *(const u16x4*)(fb + (size_t)cq[q] * HF + lane * 4);
#pragma unroll
      for (int q = 0; q < 8; ++q) {
        s_own += wq[q];
        acc.x = fmaf(wq[q], bf2f(f[q][0]), acc.x);
        acc.y = fmaf(wq[q], bf2f(f[q][1]), acc.y);
        acc.z = fmaf(wq[q], bf2f(f[q][2]), acc.z);
        acc.w = fmaf(wq[q], bf2f(f[q][3]), acc.w);
      }
    }
  }
  const float rs = (s_own > 0.f) ? __frcp_rn(s_own) : 0.f;
  float4 b4 = ((const float4*)bias)[lane];           // bias flat [H][64]
  float4 o;
  o.x = fmaxf(fmaf(acc.x, rs, b4.x), 0.f);
  o.y = fmaxf(fmaf(acc.y, rs, b4.y), 0.f);
  o.z = fmaxf(fmaf(acc.z, rs, b4.z), 0.f);
  o.w = fmaxf(fmaf(acc.w, rs, b4.w), 0.f);
  ((float4*)out)[(size_t)i * 64 + lane] = o;
}

// ---------------- launch -----------------------------------------------------
extern "C" void kernel_launch(void* const* d_in, const int* in_sizes, int n_in,
                              void* d_out, int out_size, void* d_ws, size_t ws_size,
                              hipStream_t stream) {
  const float* x       = (const float*)d_in[0];
  const float* W       = (const float*)d_in[1];
  const float* a_self  = (const float*)d_in[2];
  const float* a_neigh = (const float*)d_in[3];
  const float* bias    = (const float*)d_in[4];
  const float* adj     = (const float*)d_in[5];
  const int*   erow    = (const int*)d_in[6];
  const int*   ecol    = (const int*)d_in[7];
  float* out = (float*)d_out;

  char* w = (char*)d_ws;
  u16*   xb     = (u16*)w;   w += 25600000;   // [NN][256] bf16
  u16*   Bt     = (u16*)w;   w += 131072;     // [256][256] bf16
  u16*   fb     = (u16*)w;   w += 25600000;   // feats bf16 [NN][256]
  float* sself  = (float*)w; w += 800000;     // [NN*4]
  float* sneigh = (float*)w; w += 800000;     // [NN*4]
  int*   counts = (int*)w;   w += 200064;
  int*   rowptr = (int*)w;   w += 200192;     // [NN+1]
  int*   cursor = (int*)w;   w += 200064;
  int2*  edata  = (int2*)w;  w += 6400000;    // [NE] {col, adj}
  int*   part   = (int*)w;   w += 1024;

  const int SCAN_B = (NN + 255) / 256;        // 196

  pre_k<<<dim3(CAST_B + BT_B + ZERO_B), dim3(256), 0, stream>>>(x, xb, W, Bt, counts);
  gemm_lg_k<<<dim3((NN + 127) / 128), dim3(512), 0, stream>>>(xb, Bt, fb, a_self, a_neigh,
                                                              sself, sneigh, NN);
  hist_k<<<dim3(NE / 256), dim3(256), 0, stream>>>(erow, counts);
  scan1_k<<<dim3(SCAN_B), dim3(256), 0, stream>>>(counts, rowptr, part, NN);
  scan2_k<<<dim3(1), dim3(256), 0, stream>>>(part, rowptr, SCAN_B, NN);
  scan3_k<<<dim3(SCAN_B), dim3(256), 0, stream>>>(rowptr, cursor, part, NN);
  scatter_k<<<dim3(NE / 256), dim3(256), 0, stream>>>(erow, ecol, adj, cursor, edata);
  node3_k<<<dim3(NN / 4), dim3(256), 0, stream>>>(rowptr, edata, (const float4*)sneigh,
                                                  (const float4*)sself, fb, bias, out);
}

// Round 4
// 194.879 us; speedup vs baseline: 1.3896x; 1.0066x over previous
//
#include <hip/hip_runtime.h>
#include <hip/hip_fp16.h>
#include <math.h>

#define NN 50000
#define NE 800000
#define FIN 256
#define FOUT 64
#define HEADS 4
#define HF 256   // HEADS*FOUT

typedef unsigned short u16;
typedef unsigned int u32;
typedef __attribute__((ext_vector_type(4))) u16 u16x4;
typedef __attribute__((ext_vector_type(8))) short short8;
typedef __attribute__((ext_vector_type(4))) float f32x4;

__device__ __forceinline__ u16 f2bf(float x) {
  u32 u = __float_as_uint(x);
  u += 0x7fffu + ((u >> 16) & 1u);          // RNE
  return (u16)(u >> 16);
}
__device__ __forceinline__ float bf2f(u16 u) {
  return __uint_as_float(((u32)u) << 16);
}
__device__ __forceinline__ void gload_lds16(u16* lds, const u16* g) {
  __builtin_amdgcn_global_load_lds(
      (const __attribute__((address_space(1))) u32*)g,
      (__attribute__((address_space(3))) u32*)lds, 16, 0, 0);
}

// ---------------- K0: fused cast_x + make_bt + zero(counts) -----------------
#define CAST_B 12500
#define BT_B   256
#define ZERO_B 196
__global__ __launch_bounds__(256) void pre_k(const float* __restrict__ x,
                                             u16* __restrict__ xb,
                                             const float* __restrict__ W,
                                             u16* __restrict__ Bt,
                                             int* __restrict__ counts) {
  const int b = blockIdx.x, tid = threadIdx.x;
  if (b < CAST_B) {
    int gid = b * 256 + tid;                 // 3,200,000 float4 slots exactly
    float4 v = ((const float4*)x)[gid];
    u16x4 o = { f2bf(v.x), f2bf(v.y), f2bf(v.z), f2bf(v.w) };
    ((u16x4*)xb)[gid] = o;
  } else if (b < CAST_B + BT_B) {
    int t = (b - CAST_B) * 256 + tid;        // 65536 exactly
    int ho = t >> 8, f = t & 255;
    int h = ho >> 6, o = ho & 63;
    Bt[t] = f2bf(W[h * (FIN * FOUT) + f * FOUT + o]);
  } else {
    int i = (b - CAST_B - BT_B) * 256 + tid;
    if (i < NN) counts[i] = 0;
  }
}

// ---------------- K1: 128x256-tile bf16 MFMA GEMM + fused logits ------------
__global__ __launch_bounds__(512) void gemm_lg_k(const u16* __restrict__ A,
                                                 const u16* __restrict__ Bt,
                                                 u16* __restrict__ C,
                                                 const float* __restrict__ a_self,
                                                 const float* __restrict__ a_neigh,
                                                 float* __restrict__ sself,
                                                 float* __restrict__ sneigh,
                                                 int M) {
  __shared__ __align__(16) u16 smA[128 * 64];
  __shared__ __align__(16) u16 smB[256 * 64];
  const int tid = threadIdx.x;
  const int m0 = blockIdx.x * 128;
  const int lane = tid & 63, wid = tid >> 6;
  const int wr = wid >> 2, wc = wid & 3;
  const int arow = tid >> 3;
  const int acol = (tid & 7) * 8;
  f32x4 acc[4][4] = {};

  for (int k0 = 0; k0 < FIN; k0 += 64) {
#pragma unroll
    for (int c = 0; c < 2; ++c) {
      int row = m0 + c * 64 + arow;
      if (row > M - 1) row = M - 1;
      gload_lds16(&smA[(c * 64 + arow) * 64 + acol], A + (size_t)row * 256 + k0 + acol);
    }
#pragma unroll
    for (int c = 0; c < 4; ++c) {
      int row = c * 64 + arow;
      gload_lds16(&smB[(c * 64 + arow) * 64 + acol], Bt + row * 256 + k0 + acol);
    }
    asm volatile("s_waitcnt vmcnt(0)" ::: "memory");
    __syncthreads();
#pragma unroll
    for (int kk = 0; kk < 2; ++kk) {
      const int kb = kk * 32 + (lane >> 4) * 8;
      short8 aF[4], bF[4];
#pragma unroll
      for (int mi = 0; mi < 4; ++mi)
        aF[mi] = *(const short8*)&smA[(wr * 64 + mi * 16 + (lane & 15)) * 64 + kb];
#pragma unroll
      for (int ni = 0; ni < 4; ++ni)
        bF[ni] = *(const short8*)&smB[(wc * 64 + ni * 16 + (lane & 15)) * 64 + kb];
#pragma unroll
      for (int mi = 0; mi < 4; ++mi)
#pragma unroll
        for (int ni = 0; ni < 4; ++ni)
          acc[mi][ni] = __builtin_amdgcn_mfma_f32_16x16x32_bf16(aF[mi], bF[ni], acc[mi][ni], 0, 0, 0);
    }
    __syncthreads();
  }
#pragma unroll
  for (int mi = 0; mi < 4; ++mi) {
#pragma unroll
    for (int ni = 0; ni < 4; ++ni) {
      f32x4 a = acc[mi][ni];
      int col = wc * 64 + ni * 16 + (lane & 15);
#pragma unroll
      for (int r = 0; r < 4; ++r) {
        int row = m0 + wr * 64 + mi * 16 + (lane >> 4) * 4 + r;
        if (row < M) C[(size_t)row * 256 + col] = f2bf(a[r]);
      }
    }
  }
  float asv[4], anv[4];
#pragma unroll
  for (int ni = 0; ni < 4; ++ni) {
    int col = wc * 64 + ni * 16 + (lane & 15);
    asv[ni] = a_self[col];
    anv[ni] = a_neigh[col];
  }
#pragma unroll
  for (int mi = 0; mi < 4; ++mi) {
#pragma unroll
    for (int r = 0; r < 4; ++r) {
      float ds = 0.f, dn = 0.f;
#pragma unroll
      for (int ni = 0; ni < 4; ++ni) {
        float v = acc[mi][ni][r];
        ds = fmaf(v, asv[ni], ds);
        dn = fmaf(v, anv[ni], dn);
      }
#pragma unroll
      for (int off = 1; off < 16; off <<= 1) {
        ds += __shfl_xor(ds, off, 64);
        dn += __shfl_xor(dn, off, 64);
      }
      if ((lane & 15) == 0) {
        int row = m0 + wr * 64 + mi * 16 + (lane >> 4) * 4 + r;
        if (row < M) {
          sself[row * 4 + wc] = ds;
          sneigh[row * 4 + wc] = dn;
        }
      }
    }
  }
}

// ---------------- K2: CSR build ---------------------------------------------
__global__ __launch_bounds__(256) void hist_k(const int* __restrict__ erow,
                                              int* __restrict__ counts) {
  int e = blockIdx.x * 256 + threadIdx.x;
  atomicAdd(&counts[erow[e]], 1);
}
__global__ __launch_bounds__(256) void scan1_k(const int* __restrict__ counts,
                                               int* __restrict__ rowptr,
                                               int* __restrict__ part, int n) {
  __shared__ int buf[256];
  int t = threadIdx.x, i = blockIdx.x * 256 + t;
  int v = (i < n) ? counts[i] : 0;
  buf[t] = v;
  __syncthreads();
  for (int off = 1; off < 256; off <<= 1) {
    int tmp = (t >= off) ? buf[t - off] : 0;
    __syncthreads();
    buf[t] += tmp;
    __syncthreads();
  }
  if (i < n) rowptr[i] = buf[t] - v;
  if (t == 255) part[blockIdx.x] = buf[255];
}
__global__ __launch_bounds__(256) void scan2_k(int* __restrict__ part,
                                               int* __restrict__ rowptr,
                                               int nb, int n) {
  __shared__ int buf[256];
  int t = threadIdx.x;
  int v = (t < nb) ? part[t] : 0;
  buf[t] = v;
  __syncthreads();
  for (int off = 1; off < 256; off <<= 1) {
    int tmp = (t >= off) ? buf[t - off] : 0;
    __syncthreads();
    buf[t] += tmp;
    __syncthreads();
  }
  if (t < nb) part[t] = buf[t] - v;
  if (t == 255) rowptr[n] = buf[255];
}
__global__ __launch_bounds__(256) void scan3_k(int* __restrict__ rowptr,
                                               int* __restrict__ cursor,
                                               const int* __restrict__ part, int n) {
  int i = blockIdx.x * 256 + threadIdx.x;
  if (i < n) {
    int r = rowptr[i] + part[blockIdx.x];
    rowptr[i] = r;
    cursor[i] = r;
  }
}

// ---------------- K3: scatter + per-edge weights (all 4 heads) --------------
__global__ __launch_bounds__(256) void scatter_wk(const int* __restrict__ erow,
                                                  const int* __restrict__ ecol,
                                                  const float* __restrict__ adj,
                                                  const float4* __restrict__ sself4,
                                                  const float4* __restrict__ sneigh4,
                                                  int* __restrict__ cursor,
                                                  int4* __restrict__ edata) {
  int e = blockIdx.x * 256 + threadIdx.x;   // grid exact: NE/256
  int r = erow[e];
  int c = ecol[e];
  float av = adj[e];
  float4 ss = sself4[r];                    // 16B gather, L2-resident (800 KB)
  float4 nb = sneigh4[c];
  float z0 = ss.x + nb.x, z1 = ss.y + nb.y, z2 = ss.z + nb.z, z3 = ss.w + nb.w;
  float w0 = __expf((z0 > 0.f ? z0 : 0.2f * z0) * av);
  float w1 = __expf((z1 > 0.f ? z1 : 0.2f * z1) * av);
  float w2 = __expf((z2 > 0.f ? z2 : 0.2f * z2) * av);
  float w3 = __expf((z3 > 0.f ? z3 : 0.2f * z3) * av);
  __half2 h01 = __floats2half2_rn(w0, w1);
  __half2 h23 = __floats2half2_rn(w2, w3);
  int p = atomicAdd(&cursor[r], 1);
  int4 o;
  o.x = c;
  o.y = (int)*(u32*)&h01;
  o.z = (int)*(u32*)&h23;
  o.w = 0;
  edata[p] = o;
}

// ---------------- K4: per-node aggregate + bias + relu ----------------------
// persistent: 1024 blocks x 4 waves; each wave strides nodes. Weights are
// precomputed (f16x2 pairs in edata). 16-deep gather pipeline.
#define NODE_BLOCKS 1024
#define NODE_WAVES (NODE_BLOCKS * 4)
__global__ __launch_bounds__(256) void node4_k(const int* __restrict__ rowptr,
                                               const int4* __restrict__ edata,
                                               const u16* __restrict__ fb,
                                               const float* __restrict__ bias,
                                               float* __restrict__ out) {
  __shared__ int c_s[4][64];
  __shared__ u32 w_s[4][64][2];
  const int tid = threadIdx.x, lane = tid & 63, w = tid >> 6;
  const int hl = lane >> 4;                    // this lane's head
  const int hw = hl >> 1, hp = hl & 1;         // which packed word / which half
  const float4 b4 = ((const float4*)bias)[lane];
  const int wave0 = blockIdx.x * 4 + w;

  for (int i = wave0; i < NN; i += NODE_WAVES) {
    const int beg = rowptr[i], deg = rowptr[i + 1] - beg;
    float s_own = 0.f;
    float4 acc = { 0.f, 0.f, 0.f, 0.f };

    for (int base = 0; base < deg; base += 64) {
      const int cnt = min(64, deg - base);
      int4 ed = edata[beg + base + min(lane, cnt - 1)];
      u32 w01 = (u32)ed.y, w23 = (u32)ed.z;
      if (lane >= cnt) { w01 = 0u; w23 = 0u; }   // f16 0x0000 == 0.0
      c_s[w][lane] = ed.x;
      w_s[w][lane][0] = w01;
      w_s[w][lane][1] = w23;
      asm volatile("s_waitcnt lgkmcnt(0)" ::: "memory");
      const int cnt16 = (cnt + 15) & ~15;
      for (int e = 0; e < cnt16; e += 16) {
        int cq[16]; float wq[16];
#pragma unroll
        for (int q = 0; q < 16; ++q) {
          cq[q] = c_s[w][e + q];
          u32 pw = w_s[w][e + q][hw];
          float2 f2 = __half22float2(*(const __half2*)&pw);
          wq[q] = hp ? f2.y : f2.x;
        }
        u16x4 f[16];
#pragma unroll
        for (int q = 0; q < 16; ++q)
          f[q] = *(const u16x4*)(fb + (size_t)cq[q] * HF + lane * 4);
#pragma unroll
        for (int q = 0; q < 16; ++q) {
          s_own += wq[q];
          acc.x = fmaf(wq[q], bf2f(f[q][0]), acc.x);
          acc.y = fmaf(wq[q], bf2f(f[q][1]), acc.y);
          acc.z = fmaf(wq[q], bf2f(f[q][2]), acc.z);
          acc.w = fmaf(wq[q], bf2f(f[q][3]), acc.w);
        }
      }
    }
    const float rs = (s_own > 0.f) ? __frcp_rn(s_own) : 0.f;
    float4 o;
    o.x = fmaxf(fmaf(acc.x, rs, b4.x), 0.f);
    o.y = fmaxf(fmaf(acc.y, rs, b4.y), 0.f);
    o.z = fmaxf(fmaf(acc.z, rs, b4.z), 0.f);
    o.w = fmaxf(fmaf(acc.w, rs, b4.w), 0.f);
    ((float4*)out)[(size_t)i * 64 + lane] = o;
  }
}

// ---------------- launch -----------------------------------------------------
extern "C" void kernel_launch(void* const* d_in, const int* in_sizes, int n_in,
                              void* d_out, int out_size, void* d_ws, size_t ws_size,
                              hipStream_t stream) {
  const float* x       = (const float*)d_in[0];
  const float* W       = (const float*)d_in[1];
  const float* a_self  = (const float*)d_in[2];
  const float* a_neigh = (const float*)d_in[3];
  const float* bias    = (const float*)d_in[4];
  const float* adj     = (const float*)d_in[5];
  const int*   erow    = (const int*)d_in[6];
  const int*   ecol    = (const int*)d_in[7];
  float* out = (float*)d_out;

  char* w = (char*)d_ws;
  u16*   xb     = (u16*)w;   w += 25600000;   // [NN][256] bf16
  u16*   Bt     = (u16*)w;   w += 131072;     // [256][256] bf16
  u16*   fb     = (u16*)w;   w += 25600000;   // feats bf16 [NN][256]
  float* sself  = (float*)w; w += 800000;     // [NN*4]
  float* sneigh = (float*)w; w += 800000;     // [NN*4]
  int*   counts = (int*)w;   w += 200064;
  int*   rowptr = (int*)w;   w += 200192;     // [NN+1]
  int*   cursor = (int*)w;   w += 200064;
  int4*  edata  = (int4*)w;  w += 12800000;   // [NE] {col, w01, w23, pad}
  int*   part   = (int*)w;   w += 1024;

  const int SCAN_B = (NN + 255) / 256;        // 196

  pre_k<<<dim3(CAST_B + BT_B + ZERO_B), dim3(256), 0, stream>>>(x, xb, W, Bt, counts);
  gemm_lg_k<<<dim3((NN + 127) / 128), dim3(512), 0, stream>>>(xb, Bt, fb, a_self, a_neigh,
                                                              sself, sneigh, NN);
  hist_k<<<dim3(NE / 256), dim3(256), 0, stream>>>(erow, counts);
  scan1_k<<<dim3(SCAN_B), dim3(256), 0, stream>>>(counts, rowptr, part, NN);
  scan2_k<<<dim3(1), dim3(256), 0, stream>>>(part, rowptr, SCAN_B, NN);
  scan3_k<<<dim3(SCAN_B), dim3(256), 0, stream>>>(rowptr, cursor, part, NN);
  scatter_wk<<<dim3(NE / 256), dim3(256), 0, stream>>>(erow, ecol, adj,
                                                       (const float4*)sself,
                                                       (const float4*)sneigh, cursor, edata);
  node4_k<<<dim3(NODE_BLOCKS), dim3(256), 0, stream>>>(rowptr, edata, fb, bias, out);
}